// Round 5
// baseline (339.426 us; speedup 1.0000x reference)
//
#include <hip/hip_runtime.h>

// Problem constants (fixed by setup_inputs)
#define N_ROWS 65536
#define KDIM   256
#define CM     190      // C*M = 19*10
#define CMP    192      // padded to 12 x 16-col tiles
#define KP     512      // concatenated K: [xbar | sqrt_xv]
#define LAMDA  (1.0f/64.0f)
#define LN_EPS 1e-5f

// Workspace layout (bytes)
#define OFF_BIAS_CM (192 * 1024)                 // after Bfrag (192KB)
#define OFF_BIAS_N  (OFF_BIAS_CM + 4096)         // bias_n: 65536 floats = 256KB
#define OFF_AOUT    (OFF_BIAS_N + 262144)        // A': 65536 x 512 bf16 = 64MB
#define WS_NEEDED   ((size_t)OFF_AOUT + (size_t)N_ROWS * KP * 2)

typedef __bf16 bf16;
typedef __attribute__((ext_vector_type(4))) __bf16 bf16x4;
typedef __attribute__((ext_vector_type(8))) __bf16 bf16x8;
typedef __attribute__((ext_vector_type(4))) float  f32x4;

// ---- DPP butterfly pieces ----
template<int CTRL>
__device__ __forceinline__ float dpp_add(float v) {
    int s = __builtin_amdgcn_update_dpp(0, __builtin_bit_cast(int, v), CTRL, 0xF, 0xF, true);
    return v + __builtin_bit_cast(float, s);
}
// sum over each 32-lane group, broadcast within the group
__device__ __forceinline__ float wred32(float v) {
    v = dpp_add<0xB1>(v);    // quad_perm(1,0,3,2): pair xor1
    v = dpp_add<0x4E>(v);    // quad_perm(2,3,0,1): pair xor2
    v = dpp_add<0x141>(v);   // row_half_mirror: pairs quads within 8
    v = dpp_add<0x140>(v);   // row_mirror: pairs 8-halves within 16
    int x = __builtin_amdgcn_ds_swizzle(__builtin_bit_cast(int, v), 0x401F); // xor16 in 32
    return v + __builtin_bit_cast(float, x);
}
// full 64-lane reduction, broadcast to all lanes
__device__ __forceinline__ float wred64(float v) {
    v = wred32(v);
    return v + __shfl_xor(v, 32, 64);
}

// Fragment chunk index, 16B chunks. Logical chunk lane Lr for (tile, ks) is
// stored at position Lr ^ (ks&7) ^ ((Lr>>3)&7): for any 8 consecutive logical
// lanes the stored low-3 bits are all distinct -> every 8-lane b128 phase
// spans all 32 banks (reads AND staging writes conflict-free).
__device__ __forceinline__ int chunk_idx(int tile, int ks, int L) {
    int p = L ^ (ks & 7) ^ ((L >> 3) & 7);
    return (tile * 16 + ks) * 64 + p;
}

// Store 4 consecutive bf16 of element-row rr, k-offset kp (kp 4-aligned).
// Element (rr, kp): ks=kp>>5, kk=kp&31, Lr = rr + 16*(kk>>3), j = kk&7.
__device__ __forceinline__ void frag_store_pk(bf16* frag, int tile, int rr, int kp,
                                              bf16x4 v) {
    int ks = kp >> 5;
    int kk = kp & 31;
    int L  = rr + 16 * (kk >> 3);
    int j  = kk & 7;
    *(bf16x4*)(frag + chunk_idx(tile, ks, L) * 8 + j) = v;
}

__device__ __forceinline__ void frag_store4(bf16* frag, int tile, int rr, int kp,
                                            float a, float b, float c, float d) {
    bf16x4 pk;
    pk[0] = (bf16)a; pk[1] = (bf16)b; pk[2] = (bf16)c; pk[3] = (bf16)d;
    frag_store_pk(frag, tile, rr, kp, pk);
}

// ---------------- Kernel 1: prototype prep -> B' fragments + bias_cm --------
// B'[cm, k<256]  = 2 * pbar[k]
// B'[cm, 256+k]  = 2*lamda*exp(0.5*pv)
// bias_cm[cm]    = -lamda * sum_k exp(pv)
__global__ void __launch_bounds__(64) proto_prep(
        const float* __restrict__ proto, const float* __restrict__ pvar,
        const float* __restrict__ eps_p, const float* __restrict__ ln_w,
        const float* __restrict__ ln_b, bf16* __restrict__ Bfrag,
        float* __restrict__ bias_cm) {
    int cm = blockIdx.x;            // 0..191 (190,191 zero pad)
    int lane = threadIdx.x;
    int ct = cm >> 4, rr = cm & 15;
    int k0 = lane * 4;
    if (cm >= CM) {
        frag_store4(Bfrag, ct, rr, k0,       0.f, 0.f, 0.f, 0.f);
        frag_store4(Bfrag, ct, rr, 256 + k0, 0.f, 0.f, 0.f, 0.f);
        if (lane == 0) bias_cm[cm] = 0.0f;
        return;
    }
    size_t roff = (size_t)cm * KDIM + k0;
    float4 P  = *(const float4*)(proto + roff);
    float4 V  = *(const float4*)(pvar + roff);
    float4 E0 = *(const float4*)(eps_p + roff);
    float4 E1 = *(const float4*)(eps_p + (size_t)CM * KDIM + roff);
    float4 Wv = *(const float4*)(ln_w + k0);
    float4 Bv = *(const float4*)(ln_b + k0);
    float xx[4] = {P.x, P.y, P.z, P.w};
    float vv[4] = {V.x, V.y, V.z, V.w};
    float e0[4] = {E0.x, E0.y, E0.z, E0.w};
    float e1[4] = {E1.x, E1.y, E1.z, E1.w};
    float w[4]  = {Wv.x, Wv.y, Wv.z, Wv.w};
    float b[4]  = {Bv.x, Bv.y, Bv.z, Bv.w};
    float sx[4], sum_ev = 0.f;
#pragma unroll
    for (int t = 0; t < 4; t++) {
        sx[t] = __expf(0.5f * vv[t]);
        sum_ev += sx[t] * sx[t];
    }
    sum_ev = wred64(sum_ev);
    float pb[4] = {0.f, 0.f, 0.f, 0.f};
#pragma unroll
    for (int r = 0; r < 2; r++) {
        const float* e = r ? e1 : e0;
        float tt[4], s1 = 0.f, s2 = 0.f;
#pragma unroll
        for (int t = 0; t < 4; t++) {
            tt[t] = e[t] * sx[t] + xx[t];
            s1 += tt[t]; s2 += tt[t] * tt[t];
        }
        s1 = wred64(s1); s2 = wred64(s2);
        float mu  = s1 * (1.0f / 256.0f);
        float var = s2 * (1.0f / 256.0f) - mu * mu;
        float inv = rsqrtf(var + LN_EPS);
        float y[4], n2 = 0.f;
#pragma unroll
        for (int t = 0; t < 4; t++) {
            y[t] = (tt[t] - mu) * inv * w[t] + b[t];
            n2 += y[t] * y[t];
        }
        n2 = wred64(n2);
        float sc = 1.0f / fmaxf(sqrtf(n2), 1e-12f);
#pragma unroll
        for (int t = 0; t < 4; t++) pb[t] += 0.5f * y[t] * sc;
    }
    frag_store4(Bfrag, ct, rr, k0, 2.f * pb[0], 2.f * pb[1], 2.f * pb[2], 2.f * pb[3]);
    frag_store4(Bfrag, ct, rr, 256 + k0, 2.f * LAMDA * sx[0], 2.f * LAMDA * sx[1],
                2.f * LAMDA * sx[2], 2.f * LAMDA * sx[3]);
    if (lane == 0) bias_cm[cm] = -LAMDA * sum_ev;
}

// ---------------- Kernel A: x-prep (pure streaming, one-shot waves) ---------
// One row per HALF-WAVE, one pass. KEY CHANGE (r5): r4 came back with
// VGPR_Count=32 -> the 8 up-front dwordx4 (32 VGPRs of payload) CANNOT all
// be in flight; the compiler serialized them into ~2-load windows (the same
// register-starved collapse as r0-r3, this time caused by launch_bounds
// (256,6) inviting a 32-VGPR allocation). Fix: (a) launch_bounds(256,4)
// -> 128-VGPR cap, registers are no longer scarce; (b) sched_barrier(0)
// after the load block -> no instruction may cross, so all 8 loads are
// emitted before the first consumer and their 32 destination VGPRs are
// simultaneously live by construction. One wave then holds 8KB in flight
// during its stall window; 16 waves/CU gives far more than the ~10-14KB/CU
// needed to saturate HBM.
__global__ void __launch_bounds__(256, 4) x_prep(
        const float* __restrict__ x, const float* __restrict__ xvar,
        const float* __restrict__ eps_x, const float* __restrict__ ln_w,
        const float* __restrict__ ln_b, bf16* __restrict__ Aout,
        float* __restrict__ bias_n) {
    int tid  = threadIdx.x;
    int wave = tid >> 6, lane = tid & 63;
    int sub  = lane & 31, half = lane >> 5;
    int row  = blockIdx.x * 8 + wave * 2 + half;
    int k0   = sub * 8;

    const size_t eoff = (size_t)N_ROWS * KDIM;
    size_t roff = (size_t)row * KDIM + k0;

    // issue all 8 independent loads up front (8KB/wave in flight)
    f32x4 V0  = *(const f32x4*)(xvar + roff);
    f32x4 V1  = *(const f32x4*)(xvar + roff + 4);
    f32x4 X0  = *(const f32x4*)(x + roff);
    f32x4 X1  = *(const f32x4*)(x + roff + 4);
    f32x4 E00 = *(const f32x4*)(eps_x + roff);
    f32x4 E01 = *(const f32x4*)(eps_x + roff + 4);
    f32x4 E10 = *(const f32x4*)(eps_x + eoff + roff);
    f32x4 E11 = *(const f32x4*)(eps_x + eoff + roff + 4);

    f32x4 w0 = *(const f32x4*)(ln_w + k0);
    f32x4 w1 = *(const f32x4*)(ln_w + k0 + 4);
    f32x4 b0 = *(const f32x4*)(ln_b + k0);
    f32x4 b1 = *(const f32x4*)(ln_b + k0 + 4);

    // compile-time fence: nothing crosses -> all loads emitted before any use
    __builtin_amdgcn_sched_barrier(0);

    float sx[8], t0[8], t1[8];
    float sev = 0.f, s10 = 0.f, s20 = 0.f, s11 = 0.f, s21 = 0.f;
#pragma unroll
    for (int t = 0; t < 4; t++) {
        float s = __expf(0.5f * V0[t]);
        sx[t] = s; sev += s * s;
        float a0 = E00[t] * s + X0[t];
        float a1 = E10[t] * s + X0[t];
        t0[t] = a0; t1[t] = a1;
        s10 += a0; s20 += a0 * a0;
        s11 += a1; s21 += a1 * a1;
    }
#pragma unroll
    for (int t = 0; t < 4; t++) {
        float s = __expf(0.5f * V1[t]);
        sx[4 + t] = s; sev += s * s;
        float a0 = E01[t] * s + X1[t];
        float a1 = E11[t] * s + X1[t];
        t0[4 + t] = a0; t1[4 + t] = a1;
        s10 += a0; s20 += a0 * a0;
        s11 += a1; s21 += a1 * a1;
    }
    s10 = wred32(s10); s20 = wred32(s20);
    s11 = wred32(s11); s21 = wred32(s21);
    sev = wred32(sev);
    float mu0  = s10 * (1.0f / 256.0f);
    float var0 = s20 * (1.0f / 256.0f) - mu0 * mu0;
    float inv0 = rsqrtf(var0 + LN_EPS);
    float mu1  = s11 * (1.0f / 256.0f);
    float var1 = s21 * (1.0f / 256.0f) - mu1 * mu1;
    float inv1 = rsqrtf(var1 + LN_EPS);
    float n20 = 0.f, n21 = 0.f;
#pragma unroll
    for (int m = 0; m < 8; m++) {
        float wm = (m < 4) ? w0[m & 3] : w1[m & 3];
        float bm = (m < 4) ? b0[m & 3] : b1[m & 3];
        float y0 = (t0[m] - mu0) * inv0 * wm + bm;
        float y1 = (t1[m] - mu1) * inv1 * wm + bm;
        t0[m] = y0; t1[m] = y1;
        n20 += y0 * y0; n21 += y1 * y1;
    }
    n20 = wred32(n20); n21 = wred32(n21);
    float sc0 = 0.5f / fmaxf(sqrtf(n20), 1e-12f);
    float sc1 = 0.5f / fmaxf(sqrtf(n21), 1e-12f);

    if (sub == 0) bias_n[row] = -LAMDA * sev;

    bf16x8 xp, sp;
#pragma unroll
    for (int m = 0; m < 8; m++) {
        xp[m] = (bf16)(t0[m] * sc0 + t1[m] * sc1);
        sp[m] = (bf16)sx[m];
    }
    size_t ob = (size_t)row * KP + k0;
    *(bf16x8*)(Aout + ob)        = xp;   // lanes 0-31 -> 512B dense per row
    *(bf16x8*)(Aout + ob + KDIM) = sp;
}

// ---------------- Kernel B: GEMM + epilogue ---------------------------------
// 64 rows/block, 512 thr. Stage: each wave reads 8 dense 1KB rows of A' and
// scatters to swizzled LDS frags (lane L holds elems 8L..8L+7 -> chunk
// (ks=L>>2, Lr=(rr&15)+16*(L&3)), conflict-free both sides). Then the
// distance-2 MFMA loop (2 row-tiles x 3 col-tiles per wave) as before.
__global__ void __launch_bounds__(512, 4) gemm_main(
        const bf16* __restrict__ Aglob, const bf16* __restrict__ Bfrag,
        const float* __restrict__ bias_n, const float* __restrict__ bias_cm,
        float* __restrict__ out) {
    __shared__ bf16 Afrag[64 * KP];     // 64 KB
    __shared__ float bias_s[64];
    int tid  = threadIdx.x;
    int wave = tid >> 6, lane = tid & 63;
    int row0 = blockIdx.x * 64;

    int ksx = lane >> 2;
    int Lr4 = 16 * (lane & 3);
#pragma unroll
    for (int r = 0; r < 8; r++) {
        int rr = wave * 8 + r;
        bf16x8 v = *(const bf16x8*)(Aglob + (size_t)(row0 + rr) * KP + lane * 8);
        *(bf16x8*)(Afrag + chunk_idx(rr >> 4, ksx, (rr & 15) + Lr4) * 8) = v;
    }
    if (tid < 64) bias_s[tid] = bias_n[row0 + tid];

    int wave_r = wave >> 2;            // 0..1 -> row-tiles {2*wave_r, 2*wave_r+1}
    int wave_c = wave & 3;             // 0..3 -> col-tiles {3*wave_c .. +2}
    f32x4 acc[3][2];
#pragma unroll
    for (int c = 0; c < 3; c++)
#pragma unroll
        for (int i = 0; i < 2; i++) acc[c][i] = (f32x4){0.f, 0.f, 0.f, 0.f};

    bf16x8 aA[3][2], aB[3][3];
    auto loadA = [&](bf16x8* dst, int ks) {
#pragma unroll
        for (int i = 0; i < 2; i++)
            dst[i] = *(const bf16x8*)(Afrag + chunk_idx(wave_r * 2 + i, ks, lane) * 8);
    };
    auto loadB = [&](bf16x8* dst, int ks) {
#pragma unroll
        for (int c = 0; c < 3; c++)
            dst[c] = *(const bf16x8*)(Bfrag + chunk_idx(wave_c * 3 + c, ks, lane) * 8);
    };
    loadB(aB[0], 0); loadB(aB[1], 1);   // L2 prefetch hides under barrier
    __syncthreads();
    loadA(aA[0], 0); loadA(aA[1], 1);   // distance-2 pipeline
#pragma unroll
    for (int ks = 0; ks < 16; ks++) {
        int cur = ks % 3;
        if (ks < 14) {
            int nxt = (ks + 2) % 3;
            loadB(aB[nxt], ks + 2);
            loadA(aA[nxt], ks + 2);
        }
#pragma unroll
        for (int ctl = 0; ctl < 3; ctl++)
#pragma unroll
            for (int i = 0; i < 2; i++)
                acc[ctl][i] = __builtin_amdgcn_mfma_f32_16x16x32_bf16(
                    aA[cur][i], aB[cur][ctl], acc[ctl][i], 0, 0, 0);
    }

    // ---- epilogue: D layout col=lane&15, row=(lane>>4)*4+reg ----
#pragma unroll
    for (int ctl = 0; ctl < 3; ctl++) {
        int col = (wave_c * 3 + ctl) * 16 + (lane & 15);
        float bcm = (col < CM) ? bias_cm[col] : 0.0f;
        bool ok = (col < CM);
#pragma unroll
        for (int i = 0; i < 2; i++) {
            int lr0 = (wave_r * 2 + i) * 16 + ((lane >> 4) << 2);
#pragma unroll
            for (int reg = 0; reg < 4; reg++) {
                int lr = lr0 + reg;
                if (ok)
                    out[(size_t)(row0 + lr) * CM + col] =
                        acc[ctl][i][reg] + bias_s[lr] + bcm - 2.0f;
            }
        }
    }
}

// ---------------- Fallback: fused kernel (small workspace) ------------------
struct Row { f32x4 V, X, E0, E1; };

__global__ void __launch_bounds__(512, 4) fused_main(
        const float* __restrict__ x, const float* __restrict__ xvar,
        const float* __restrict__ eps_x, const float* __restrict__ ln_w,
        const float* __restrict__ ln_b, const bf16* __restrict__ Bfrag,
        const float* __restrict__ bias_cm, float* __restrict__ out) {
    __shared__ bf16 Afrag[64 * KP];     // 64 KB
    __shared__ float bias_n_s[64];
    int tid  = threadIdx.x;
    int wave = tid >> 6, lane = tid & 63;
    int row0 = blockIdx.x * 64;
    int rbase = row0 + wave * 8;
    int k0 = lane * 4;

    f32x4 wv = *(const f32x4*)(ln_w + k0);
    f32x4 bv = *(const f32x4*)(ln_b + k0);
    const size_t eoff = (size_t)N_ROWS * KDIM;

    Row rb[4];
    auto load_row = [&](Row& r, int rr) {
        size_t roff = (size_t)(rbase + rr) * KDIM + k0;
        r.V  = *(const f32x4*)(xvar + roff);
        r.X  = *(const f32x4*)(x + roff);
        r.E0 = *(const f32x4*)(eps_x + roff);
        r.E1 = *(const f32x4*)(eps_x + eoff + roff);
    };
#pragma unroll
    for (int r = 0; r < 4; r++) load_row(rb[r], r);

#pragma unroll
    for (int r = 0; r < 8; r++) {
        f32x4 V = rb[r & 3].V, X = rb[r & 3].X, E0 = rb[r & 3].E0, E1 = rb[r & 3].E1;
        if (r < 4) load_row(rb[r & 3], r + 4);

        float sx[4], t0[4], t1[4];
        float sev = 0.f, s10 = 0.f, s20 = 0.f, s11 = 0.f, s21 = 0.f;
#pragma unroll
        for (int t = 0; t < 4; t++) {
            float s = __expf(0.5f * V[t]);
            sx[t] = s;
            sev += s * s;
            float a0 = E0[t] * s + X[t];
            float a1 = E1[t] * s + X[t];
            t0[t] = a0; t1[t] = a1;
            s10 += a0; s20 += a0 * a0;
            s11 += a1; s21 += a1 * a1;
        }
        s10 = wred64(s10); s20 = wred64(s20);
        s11 = wred64(s11); s21 = wred64(s21);
        sev = wred64(sev);
        float mu0  = s10 * (1.0f / 256.0f);
        float var0 = s20 * (1.0f / 256.0f) - mu0 * mu0;
        float inv0 = rsqrtf(var0 + LN_EPS);
        float mu1  = s11 * (1.0f / 256.0f);
        float var1 = s21 * (1.0f / 256.0f) - mu1 * mu1;
        float inv1 = rsqrtf(var1 + LN_EPS);
        float n20 = 0.f, n21 = 0.f;
#pragma unroll
        for (int t = 0; t < 4; t++) {
            float y0 = (t0[t] - mu0) * inv0 * wv[t] + bv[t];
            float y1 = (t1[t] - mu1) * inv1 * wv[t] + bv[t];
            t0[t] = y0; t1[t] = y1;
            n20 += y0 * y0; n21 += y1 * y1;
        }
        n20 = wred64(n20); n21 = wred64(n21);
        float sc0 = 0.5f / fmaxf(sqrtf(n20), 1e-12f);
        float sc1 = 0.5f / fmaxf(sqrtf(n21), 1e-12f);

        int rr = wave * 8 + r;
        if (lane == 0) bias_n_s[rr] = -LAMDA * sev;

        bf16x4 xp, sp;
#pragma unroll
        for (int t = 0; t < 4; t++) {
            xp[t] = (bf16)(t0[t] * sc0 + t1[t] * sc1);
            sp[t] = (bf16)sx[t];
        }
        int tile = rr >> 4, r16 = rr & 15;
        frag_store_pk(Afrag, tile, r16, k0,       xp);
        frag_store_pk(Afrag, tile, r16, 256 + k0, sp);
    }

    int wave_r = wave >> 2;
    int wave_c = wave & 3;
    f32x4 acc[3][2];
#pragma unroll
    for (int c = 0; c < 3; c++)
#pragma unroll
        for (int i = 0; i < 2; i++) acc[c][i] = (f32x4){0.f, 0.f, 0.f, 0.f};

    bf16x8 aA[3][2], aB[3][3];
    auto loadA = [&](bf16x8* dst, int ks) {
#pragma unroll
        for (int i = 0; i < 2; i++)
            dst[i] = *(const bf16x8*)(Afrag + chunk_idx(wave_r * 2 + i, ks, lane) * 8);
    };
    auto loadB = [&](bf16x8* dst, int ks) {
#pragma unroll
        for (int c = 0; c < 3; c++)
            dst[c] = *(const bf16x8*)(Bfrag + chunk_idx(wave_c * 3 + c, ks, lane) * 8);
    };
    loadB(aB[0], 0);
    __syncthreads();
    loadA(aA[0], 0);
    loadB(aB[1], 1); loadA(aA[1], 1);
#pragma unroll
    for (int ks = 0; ks < 16; ks++) {
        int cur = ks % 3;
        if (ks < 14) {
            int nxt = (ks + 2) % 3;
            loadB(aB[nxt], ks + 2);
            loadA(aA[nxt], ks + 2);
        }
#pragma unroll
        for (int ctl = 0; ctl < 3; ctl++)
#pragma unroll
            for (int i = 0; i < 2; i++)
                acc[ctl][i] = __builtin_amdgcn_mfma_f32_16x16x32_bf16(
                    aA[cur][i], aB[cur][ctl], acc[ctl][i], 0, 0, 0);
    }

#pragma unroll
    for (int ctl = 0; ctl < 3; ctl++) {
        int col = (wave_c * 3 + ctl) * 16 + (lane & 15);
        float bcm = (col < CM) ? bias_cm[col] : 0.0f;
        bool ok = (col < CM);
#pragma unroll
        for (int i = 0; i < 2; i++) {
            int lr0 = (wave_r * 2 + i) * 16 + ((lane >> 4) << 2);
#pragma unroll
            for (int reg = 0; reg < 4; reg++) {
                int lr = lr0 + reg;
                if (ok)
                    out[(size_t)(row0 + lr) * CM + col] =
                        acc[ctl][i][reg] + bias_n_s[lr] + bcm - 2.0f;
            }
        }
    }
}

extern "C" void kernel_launch(void* const* d_in, const int* in_sizes, int n_in,
                              void* d_out, int out_size, void* d_ws, size_t ws_size,
                              hipStream_t stream) {
    const float* x     = (const float*)d_in[0];
    const float* xvar  = (const float*)d_in[1];
    const float* proto = (const float*)d_in[2];
    const float* pvar  = (const float*)d_in[3];
    const float* eps_x = (const float*)d_in[4];
    const float* eps_p = (const float*)d_in[5];
    const float* ln_w  = (const float*)d_in[6];
    const float* ln_b  = (const float*)d_in[7];
    float* out = (float*)d_out;

    bf16*  Bfrag   = (bf16*)d_ws;
    float* bias_cm = (float*)((char*)d_ws + OFF_BIAS_CM);

    proto_prep<<<CMP, 64, 0, stream>>>(proto, pvar, eps_p, ln_w, ln_b, Bfrag, bias_cm);

    if (ws_size >= WS_NEEDED) {
        float* bias_n = (float*)((char*)d_ws + OFF_BIAS_N);
        bf16*  Aout   = (bf16*)((char*)d_ws + OFF_AOUT);
        x_prep<<<N_ROWS / 8, 256, 0, stream>>>(x, xvar, eps_x, ln_w, ln_b, Aout, bias_n);
        gemm_main<<<N_ROWS / 64, 512, 0, stream>>>(Aout, Bfrag, bias_n, bias_cm, out);
    } else {
        fused_main<<<N_ROWS / 64, 512, 0, stream>>>(x, xvar, eps_x, ln_w, ln_b, Bfrag, bias_cm, out);
    }
}

// Round 6
// 303.503 us; speedup vs baseline: 1.1184x; 1.1184x over previous
//
#include <hip/hip_runtime.h>

// Problem constants (fixed by setup_inputs)
#define N_ROWS 65536
#define KDIM   256
#define CM     190      // C*M = 19*10
#define CMP    192      // padded to 12 x 16-col tiles
#define KP     512      // concatenated K: [xbar | sqrt_xv]
#define LAMDA  (1.0f/64.0f)
#define LN_EPS 1e-5f

typedef __bf16 bf16;
typedef __attribute__((ext_vector_type(4))) __bf16 bf16x4;
typedef __attribute__((ext_vector_type(8))) __bf16 bf16x8;
typedef __attribute__((ext_vector_type(4))) float  f32x4;

// ---- DPP butterfly pieces ----
template<int CTRL>
__device__ __forceinline__ float dpp_add(float v) {
    int s = __builtin_amdgcn_update_dpp(0, __builtin_bit_cast(int, v), CTRL, 0xF, 0xF, true);
    return v + __builtin_bit_cast(float, s);
}
// sum over each 32-lane group, broadcast within the group
__device__ __forceinline__ float wred32(float v) {
    v = dpp_add<0xB1>(v);    // quad_perm(1,0,3,2): pair xor1
    v = dpp_add<0x4E>(v);    // quad_perm(2,3,0,1): pair xor2
    v = dpp_add<0x141>(v);   // row_half_mirror: pairs quads within 8
    v = dpp_add<0x140>(v);   // row_mirror: pairs 8-halves within 16
    int x = __builtin_amdgcn_ds_swizzle(__builtin_bit_cast(int, v), 0x401F); // xor16 in 32
    return v + __builtin_bit_cast(float, x);
}
// full 64-lane reduction (proto_prep only)
__device__ __forceinline__ float wred64(float v) {
    v = wred32(v);
    return v + __shfl_xor(v, 32, 64);
}

// Fragment chunk index, 16B chunks. Logical chunk lane Lr for (tile, ks) is
// stored at position Lr ^ (ks&7) ^ ((Lr>>3)&7): for any 8 consecutive logical
// lanes the stored low-3 bits are all distinct -> every 8-lane b128 phase
// spans all 32 banks (reads AND staging writes conflict-free).
__device__ __forceinline__ int chunk_idx(int tile, int ks, int L) {
    int p = L ^ (ks & 7) ^ ((L >> 3) & 7);
    return (tile * 16 + ks) * 64 + p;
}

// Store 4 consecutive bf16 of element-row rr, k-offset kp (kp 4-aligned).
// Element (rr, kp): ks=kp>>5, kk=kp&31, Lr = rr + 16*(kk>>3), j = kk&7.
__device__ __forceinline__ void frag_store4(bf16* frag, int tile, int rr, int kp,
                                            float a, float b, float c, float d) {
    int ks = kp >> 5;
    int kk = kp & 31;
    int L  = rr + 16 * (kk >> 3);
    int j  = kk & 7;
    bf16x4 pk;
    pk[0] = (bf16)a; pk[1] = (bf16)b; pk[2] = (bf16)c; pk[3] = (bf16)d;
    *(bf16x4*)(frag + chunk_idx(tile, ks, L) * 8 + j) = pk;
}

// ---------------- Kernel 1: prototype prep -> B' fragments + bias_cm --------
// B'[cm, k<256]  = 2 * pbar[k]
// B'[cm, 256+k]  = 2*lamda*exp(0.5*pv)
// bias_cm[cm]    = -lamda * sum_k exp(pv)
__global__ void __launch_bounds__(64) proto_prep(
        const float* __restrict__ proto, const float* __restrict__ pvar,
        const float* __restrict__ eps_p, const float* __restrict__ ln_w,
        const float* __restrict__ ln_b, bf16* __restrict__ Bfrag,
        float* __restrict__ bias_cm) {
    int cm = blockIdx.x;            // 0..191 (190,191 zero pad)
    int lane = threadIdx.x;
    int ct = cm >> 4, rr = cm & 15;
    int k0 = lane * 4;
    if (cm >= CM) {
        frag_store4(Bfrag, ct, rr, k0,       0.f, 0.f, 0.f, 0.f);
        frag_store4(Bfrag, ct, rr, 256 + k0, 0.f, 0.f, 0.f, 0.f);
        if (lane == 0) bias_cm[cm] = 0.0f;
        return;
    }
    size_t roff = (size_t)cm * KDIM + k0;
    float4 P  = *(const float4*)(proto + roff);
    float4 V  = *(const float4*)(pvar + roff);
    float4 E0 = *(const float4*)(eps_p + roff);
    float4 E1 = *(const float4*)(eps_p + (size_t)CM * KDIM + roff);
    float4 Wv = *(const float4*)(ln_w + k0);
    float4 Bv = *(const float4*)(ln_b + k0);
    float xx[4] = {P.x, P.y, P.z, P.w};
    float vv[4] = {V.x, V.y, V.z, V.w};
    float e0[4] = {E0.x, E0.y, E0.z, E0.w};
    float e1[4] = {E1.x, E1.y, E1.z, E1.w};
    float w[4]  = {Wv.x, Wv.y, Wv.z, Wv.w};
    float b[4]  = {Bv.x, Bv.y, Bv.z, Bv.w};
    float sx[4], sum_ev = 0.f;
#pragma unroll
    for (int t = 0; t < 4; t++) {
        sx[t] = __expf(0.5f * vv[t]);
        sum_ev += sx[t] * sx[t];
    }
    sum_ev = wred64(sum_ev);
    float pb[4] = {0.f, 0.f, 0.f, 0.f};
#pragma unroll
    for (int r = 0; r < 2; r++) {
        const float* e = r ? e1 : e0;
        float tt[4], s1 = 0.f, s2 = 0.f;
#pragma unroll
        for (int t = 0; t < 4; t++) {
            tt[t] = e[t] * sx[t] + xx[t];
            s1 += tt[t]; s2 += tt[t] * tt[t];
        }
        s1 = wred64(s1); s2 = wred64(s2);
        float mu  = s1 * (1.0f / 256.0f);
        float var = s2 * (1.0f / 256.0f) - mu * mu;
        float inv = rsqrtf(var + LN_EPS);
        float y[4], n2 = 0.f;
#pragma unroll
        for (int t = 0; t < 4; t++) {
            y[t] = (tt[t] - mu) * inv * w[t] + b[t];
            n2 += y[t] * y[t];
        }
        n2 = wred64(n2);
        float sc = 1.0f / fmaxf(sqrtf(n2), 1e-12f);
#pragma unroll
        for (int t = 0; t < 4; t++) pb[t] += 0.5f * y[t] * sc;
    }
    frag_store4(Bfrag, ct, rr, k0, 2.f * pb[0], 2.f * pb[1], 2.f * pb[2], 2.f * pb[3]);
    frag_store4(Bfrag, ct, rr, 256 + k0, 2.f * LAMDA * sx[0], 2.f * LAMDA * sx[1],
                2.f * LAMDA * sx[2], 2.f * LAMDA * sx[3]);
    if (lane == 0) bias_cm[cm] = -LAMDA * sum_ev;
}

// ---------------- Kernel 2: fused x-prep + GEMM + epilogue ------------------
// FUSED is the right architecture: 6 structural probes (r0-r5) all pinned at
// 1.6-1.9 TB/s HBM regardless of occupancy/coalescing/MLP structure, so the
// split's extra 128MB A' round-trip is pure loss (fused benches 312 vs split
// 339-349). Phase 1 here uses the best-measured layout (r4 one-shot style):
// row per HALF-WAVE, lane owns 8 elems, 8-load/8KB bursts, wred32-only, with
// distance-1 burst pipelining pinned by sched_barrier (r5 proved VGPR=36 ->
// bursts live; here 2 bursts = 64 payload VGPRs under the 128 cap).
// eps_x loads are non-temporal (zero reuse) so x/xvar stay cache-resident.
// Phase 2: 2 row-tiles x 3 col-tiles per wave, distance-2 (unchanged, known
// correct since r1).
struct Burst { f32x4 V0, V1, X0, X1, E00, E01, E10, E11; };

__global__ void __launch_bounds__(512, 4) fused_main(
        const float* __restrict__ x, const float* __restrict__ xvar,
        const float* __restrict__ eps_x, const float* __restrict__ ln_w,
        const float* __restrict__ ln_b, const bf16* __restrict__ Bfrag,
        const float* __restrict__ bias_cm, float* __restrict__ out) {
    __shared__ bf16 Afrag[64 * KP];     // 64 KB
    __shared__ float bias_n_s[64];
    int tid  = threadIdx.x;
    int wave = tid >> 6, lane = tid & 63;
    int sub  = lane & 31, half = lane >> 5;
    int row0 = blockIdx.x * 64;
    int rbase = row0 + wave * 8;        // 8 rows per wave (4 batches of 2)
    int k0 = sub * 8;                   // this lane's 8 elements of its row

    const size_t eoff = (size_t)N_ROWS * KDIM;

    f32x4 w0 = *(const f32x4*)(ln_w + k0);
    f32x4 w1 = *(const f32x4*)(ln_w + k0 + 4);
    f32x4 b0 = *(const f32x4*)(ln_b + k0);
    f32x4 b1 = *(const f32x4*)(ln_b + k0 + 4);

    Burst bb[2];
    auto load_burst = [&](Burst& B, int batch) {
        size_t roff = (size_t)(rbase + batch * 2 + half) * KDIM + k0;
        B.V0  = *(const f32x4*)(xvar + roff);
        B.V1  = *(const f32x4*)(xvar + roff + 4);
        B.X0  = *(const f32x4*)(x + roff);
        B.X1  = *(const f32x4*)(x + roff + 4);
        B.E00 = __builtin_nontemporal_load((const f32x4*)(eps_x + roff));
        B.E01 = __builtin_nontemporal_load((const f32x4*)(eps_x + roff + 4));
        B.E10 = __builtin_nontemporal_load((const f32x4*)(eps_x + eoff + roff));
        B.E11 = __builtin_nontemporal_load((const f32x4*)(eps_x + eoff + roff + 4));
    };

    load_burst(bb[0], 0);
    __builtin_amdgcn_sched_barrier(0);   // pin: burst 0 fully issued first

#pragma unroll
    for (int batch = 0; batch < 4; batch++) {
        if (batch < 3) {
            load_burst(bb[(batch + 1) & 1], batch + 1);
            __builtin_amdgcn_sched_barrier(0);   // next burst issued before compute
        }
        Burst& B = bb[batch & 1];

        float sx[8], t0[8], t1[8];
        float sev = 0.f, s10 = 0.f, s20 = 0.f, s11 = 0.f, s21 = 0.f;
#pragma unroll
        for (int t = 0; t < 4; t++) {
            float s = __expf(0.5f * B.V0[t]);
            sx[t] = s; sev += s * s;
            float a0 = B.E00[t] * s + B.X0[t];
            float a1 = B.E10[t] * s + B.X0[t];
            t0[t] = a0; t1[t] = a1;
            s10 += a0; s20 += a0 * a0;
            s11 += a1; s21 += a1 * a1;
        }
#pragma unroll
        for (int t = 0; t < 4; t++) {
            float s = __expf(0.5f * B.V1[t]);
            sx[4 + t] = s; sev += s * s;
            float a0 = B.E01[t] * s + B.X1[t];
            float a1 = B.E11[t] * s + B.X1[t];
            t0[4 + t] = a0; t1[4 + t] = a1;
            s10 += a0; s20 += a0 * a0;
            s11 += a1; s21 += a1 * a1;
        }
        s10 = wred32(s10); s20 = wred32(s20);
        s11 = wred32(s11); s21 = wred32(s21);
        sev = wred32(sev);
        float mu0  = s10 * (1.0f / 256.0f);
        float var0 = s20 * (1.0f / 256.0f) - mu0 * mu0;
        float inv0 = rsqrtf(var0 + LN_EPS);
        float mu1  = s11 * (1.0f / 256.0f);
        float var1 = s21 * (1.0f / 256.0f) - mu1 * mu1;
        float inv1 = rsqrtf(var1 + LN_EPS);
        float n20 = 0.f, n21 = 0.f;
#pragma unroll
        for (int m = 0; m < 8; m++) {
            float wm = (m < 4) ? w0[m & 3] : w1[m & 3];
            float bm = (m < 4) ? b0[m & 3] : b1[m & 3];
            float y0 = (t0[m] - mu0) * inv0 * wm + bm;
            float y1 = (t1[m] - mu1) * inv1 * wm + bm;
            t0[m] = y0; t1[m] = y1;
            n20 += y0 * y0; n21 += y1 * y1;
        }
        n20 = wred32(n20); n21 = wred32(n21);
        float sc0 = 0.5f / fmaxf(sqrtf(n20), 1e-12f);
        float sc1 = 0.5f / fmaxf(sqrtf(n21), 1e-12f);

        int rr = wave * 8 + batch * 2 + half;   // row within the 64-row block
        if (sub == 0) bias_n_s[rr] = -LAMDA * sev;

        bf16x8 xp, sp;
#pragma unroll
        for (int m = 0; m < 8; m++) {
            xp[m] = (bf16)(t0[m] * sc0 + t1[m] * sc1);
            sp[m] = (bf16)sx[m];
        }
        // lane owns elems k0..k0+7: ks=sub>>2, Lr=(rr&15)+16*(sub&3)
        int tile = rr >> 4, r16 = rr & 15;
        int ks = sub >> 2;
        int Lr = r16 + 16 * (sub & 3);
        *(bf16x8*)(Afrag + chunk_idx(tile, ks, Lr) * 8)     = xp;
        *(bf16x8*)(Afrag + chunk_idx(tile, 8 + ks, Lr) * 8) = sp;
    }
    __syncthreads();

    // ---- phase 2: GEMM. wave_r picks 2 row-tiles, wave_c picks 3 col-tiles.
    int wave_r = wave >> 2;            // 0..1 -> row-tiles {2*wave_r, 2*wave_r+1}
    int wave_c = wave & 3;             // 0..3 -> col-tiles {3*wave_c .. +2}
    f32x4 acc[3][2];
#pragma unroll
    for (int c = 0; c < 3; c++)
#pragma unroll
        for (int i = 0; i < 2; i++) acc[c][i] = (f32x4){0.f, 0.f, 0.f, 0.f};

    bf16x8 aA[3][2], aB[3][3];
    auto loadA = [&](bf16x8* dst, int ks) {
#pragma unroll
        for (int i = 0; i < 2; i++)
            dst[i] = *(const bf16x8*)(Afrag + chunk_idx(wave_r * 2 + i, ks, lane) * 8);
    };
    auto loadB = [&](bf16x8* dst, int ks) {
#pragma unroll
        for (int c = 0; c < 3; c++)
            dst[c] = *(const bf16x8*)(Bfrag + chunk_idx(wave_c * 3 + c, ks, lane) * 8);
    };
    loadA(aA[0], 0); loadB(aB[0], 0);
    loadA(aA[1], 1); loadB(aB[1], 1);   // distance-2 pipeline
#pragma unroll
    for (int ks = 0; ks < 16; ks++) {
        int cur = ks % 3;
        if (ks < 14) {
            int nxt = (ks + 2) % 3;
            loadB(aB[nxt], ks + 2);
            loadA(aA[nxt], ks + 2);
        }
#pragma unroll
        for (int ctl = 0; ctl < 3; ctl++)
#pragma unroll
            for (int i = 0; i < 2; i++)
                acc[ctl][i] = __builtin_amdgcn_mfma_f32_16x16x32_bf16(
                    aA[cur][i], aB[cur][ctl], acc[ctl][i], 0, 0, 0);
    }

    // ---- epilogue: D layout col=lane&15, row=(lane>>4)*4+reg ----
#pragma unroll
    for (int ctl = 0; ctl < 3; ctl++) {
        int col = (wave_c * 3 + ctl) * 16 + (lane & 15);
        float bcm = (col < CM) ? bias_cm[col] : 0.0f;
        bool ok = (col < CM);
#pragma unroll
        for (int i = 0; i < 2; i++) {
            int lr0 = (wave_r * 2 + i) * 16 + ((lane >> 4) << 2);
#pragma unroll
            for (int reg = 0; reg < 4; reg++) {
                int lr = lr0 + reg;
                if (ok)
                    out[(size_t)(row0 + lr) * CM + col] =
                        acc[ctl][i][reg] + bias_n_s[lr] + bcm - 2.0f;
            }
        }
    }
}

extern "C" void kernel_launch(void* const* d_in, const int* in_sizes, int n_in,
                              void* d_out, int out_size, void* d_ws, size_t ws_size,
                              hipStream_t stream) {
    const float* x     = (const float*)d_in[0];
    const float* xvar  = (const float*)d_in[1];
    const float* proto = (const float*)d_in[2];
    const float* pvar  = (const float*)d_in[3];
    const float* eps_x = (const float*)d_in[4];
    const float* eps_p = (const float*)d_in[5];
    const float* ln_w  = (const float*)d_in[6];
    const float* ln_b  = (const float*)d_in[7];
    float* out = (float*)d_out;

    bf16*  Bfrag   = (bf16*)d_ws;                                   // 192*512*2 B
    float* bias_cm = (float*)((char*)d_ws + (size_t)CMP * KP * 2);  // 192 floats

    proto_prep<<<CMP, 64, 0, stream>>>(proto, pvar, eps_p, ln_w, ln_b, Bfrag, bias_cm);
    fused_main<<<N_ROWS / 64, 512, 0, stream>>>(x, xvar, eps_x, ln_w, ln_b, Bfrag, bias_cm, out);
}